// Round 6
// baseline (489.625 us; speedup 1.0000x reference)
//
#include <hip/hip_runtime.h>
#include <stdint.h>

// ---------------------------------------------------------------------------
// R13: register-economy round on R12's wave-per-chunk mids.
// R12 post-mortem: midC FETCH 143/WRITE 89 MB vs ideal 102/27 SYMMETRIC
// excess = scratch spills. CSV VGPR_Count=64 is arch-VGPR only; +64 AGPR acc
// = at the 128 cap of (256,4); the unroll-4 pq loop hoisted 4 quads of
// A-frags past the cap -> spill traffic, and the LDS-staged out-store fix
// changed nothing (excess was never the out stores).
// Changes (midB/midC only; prep/midA/fixk = R12 verbatim):
//  - #pragma unroll 1 on the pq loop (live state = one quad).
//  - (256,3) + explicit next-quad prefetch: 6 global loads issued before the
//    current quad's MFMA/scan -> ~6 KB/wave in flight for latency hiding.
// ---------------------------------------------------------------------------

#define BB 4
#define SP 65536
#define SS 196608
#define CI 1024                 // 64-px chunks per batch
#define NG 16                   // groups per batch (64 chunks each)
#define INVN (1.0f / 196608.0f)

typedef __attribute__((ext_vector_type(8))) _Float16 half8;
typedef __attribute__((ext_vector_type(4))) float    f32x4;

// ---------------- prep: histograms + weight prep + Ggrp zero ----------------
__global__ __launch_bounds__(256)
void prep(const int* __restrict__ ex, const float* __restrict__ W0,
          const float* __restrict__ b0, const float* __restrict__ Wr,
          const float* __restrict__ Wfin,
          _Float16* __restrict__ Wt16, float* __restrict__ Wd32T,
          _Float16* __restrict__ Wf16p,
          float* __restrict__ Wf32, float* __restrict__ tab32,
          int* __restrict__ Hsub, int* __restrict__ Hqrt,
          float* __restrict__ Gz)
{
    __shared__ int hist[16][24];
    int tid = threadIdx.x, bi = blockIdx.x;        // 256 blocks
    int b = bi >> 6, g = (bi >> 2) & 15, q = bi & 3;  // quarter-group = 16 chunks
    for (int i = tid; i < 384; i += 256) hist[i / 24][i % 24] = 0;
    __syncthreads();
    for (int it = 0; it < 4; ++it) {
        int pl = it * 256 + tid;                   // 0..1023 within quarter
        const int* ep = ex + ((size_t)b * SP + g * 4096 + q * 1024 + pl) * 3;
        int j = pl >> 6;                           // chunk within quarter
        atomicAdd(&hist[j][ep[0]], 1);
        atomicAdd(&hist[j][8 + ep[1]], 1);
        atomicAdd(&hist[j][16 + ep[2]], 1);
    }
    __syncthreads();
    for (int i = tid; i < 384; i += 256) {
        int j = i / 24, cv = i % 24;
        Hsub[(size_t)(b * CI + g * 64 + q * 16 + j) * 24 + cv] = hist[j][cv];
    }
    if (tid < 24) {
        int s = 0;
        for (int j = 0; j < 16; ++j) s += hist[j][tid];
        Hqrt[((size_t)(b * NG + g) * 4 + q) * 24 + tid] = s;   // non-atomic
    }
    {   // weight prep + Ggrp zeroing (all 256 blocks share)
        int i0 = bi * 256 + tid, nth = 256 * 256;
        for (int idx = i0; idx < 12288; idx += nth)     // Ggrp1..3 zero
            Gz[idx] = 0.f;
        for (int idx = i0; idx < 36864; idx += nth) {   // Wt16/Wd32T [l][c][f][d]
            int d = idx & 63, f = (idx >> 6) & 63, lc = idx >> 12;
            float v = Wr[(size_t)(lc * 64 + d) * 64 + f];
            Wt16[idx]  = (_Float16)v;
            Wd32T[idx] = v;
        }
        for (int idx = i0; idx < 3072; idx += nth) {    // Wf16p[c][n16][d]
            int d = idx & 63, n = (idx >> 6) & 15, c = idx >> 10;
            Wf16p[idx] = (n < 8) ? (_Float16)Wfin[(size_t)(c * 64 + d) * 8 + n]
                                 : (_Float16)0.f;
        }
        for (int idx = i0; idx < 1536; idx += nth) {    // Wf32[ck][d]
            int d = idx & 63, ck = idx >> 6;
            Wf32[idx] = Wfin[(size_t)((ck >> 3) * 64 + d) * 8 + (ck & 7)];
        }
        for (int idx = i0; idx < 1536; idx += nth) {    // tab32[cv][f]
            int f = idx & 63, v = (idx >> 6) & 7, c = idx >> 9;
            float xv = v * 0.25f - 1.0f;
            tab32[idx] = fmaxf(W0[c * 64 + f] * xv + b0[c * 64 + f], 0.f);
        }
    }
}

// ---------------- midA: R7-exact layer0 (LUT, hist carry) + dense1 -> Y -----
__global__ __launch_bounds__(256, 4)
void midA(const int* __restrict__ ex,
          const int* __restrict__ Hsub, const int* __restrict__ Hqrt,
          const float* __restrict__ tab32,
          const _Float16* __restrict__ W16, const float* __restrict__ Wd32,
          const float* __restrict__ bias, _Float16* __restrict__ Y,
          float* __restrict__ A64, float* __restrict__ Ggrp)
{
    __shared__ float stab[1536];
    __shared__ __align__(16) _Float16 bounce3[3][64 * 72];
    __shared__ float segwt[3][4][64];
    __shared__ float basearr[192];
    __shared__ float hpart[4][24];
    __shared__ float carry[64];

    int tid = threadIdx.x, bi = blockIdx.x;
    int b = bi >> 10, ci = bi & 1023, g = ci >> 6, cr = ci & 63;
    int w = tid >> 6, ln = tid & 63, lm = ln & 15, lq = ln >> 4;
    int P0 = ci * 64;

    for (int i = tid; i < 1536; i += 256) stab[i] = tab32[i];
    if (ln < 24) {                             // distributed hist prefix
        float s = 0.f;
        for (int j = w; j < g; j += 4) {
            const int* hq = Hqrt + ((size_t)(b * NG + j) * 4) * 24 + ln;
            s += (float)(hq[0] + hq[24] + hq[48] + hq[72]);
        }
        const int* hp = Hsub + (size_t)(b * CI + g * 64) * 24 + ln;
        for (int j = w; j < cr; j += 4) s += (float)hp[j * 24];
        hpart[w][ln] = s;
    }
    __syncthreads();                           // B1: stab + hpart

    float y0[3][16];
    {
#pragma unroll
        for (int p = 0; p < 16; ++p) {
            const int* ep = ex + ((size_t)b * SP + P0 + w * 16 + p) * 3;
            y0[0][p] = stab[ep[0] * 64 + ln];
            y0[1][p] = stab[(8 + ep[1]) * 64 + ln];
            y0[2][p] = stab[(16 + ep[2]) * 64 + ln];
        }
#pragma unroll
        for (int c = 0; c < 3; ++c)
#pragma unroll
            for (int p = 1; p < 16; ++p) y0[c][p] += y0[c][p - 1];
#pragma unroll
        for (int c = 0; c < 3; ++c) segwt[c][w][ln] = y0[c][15];
    }
    if (tid < 64) {                            // layer-0 carry from hist
        float c0 = 0.f;
#pragma unroll
        for (int cv = 0; cv < 24; ++cv) {
            float cnt = hpart[0][cv] + hpart[1][cv] + hpart[2][cv] + hpart[3][cv];
            c0 += cnt * stab[cv * 64 + tid];
        }
        carry[tid] = c0;
    }
    __syncthreads();                           // B2: segwt + carry

    {   // combine channels -> bounce (layer-0 chunk-local flattened cumsum)
        float off0[3];
#pragma unroll
        for (int c = 0; c < 3; ++c) {
            float o = 0.f;
            for (int w2 = 0; w2 < w; ++w2) o += segwt[c][w2][ln];
            off0[c] = o;
        }
#pragma unroll
        for (int p = 0; p < 16; ++p) {
            float S0 = y0[0][p] + off0[0], S1 = y0[1][p] + off0[1], S2 = y0[2][p] + off0[2];
            float P1 = p ? y0[1][p - 1] + off0[1] : off0[1];
            float P2 = p ? y0[2][p - 1] + off0[2] : off0[2];
            int row = w * 16 + p;
            bounce3[0][row * 72 + ln] = (_Float16)(S0 + P1 + P2);
            bounce3[1][row * 72 + ln] = (_Float16)(S0 + S1 + P2);
            bounce3[2][row * 72 + ln] = (_Float16)(S0 + S1 + S2);
        }
    }
    if (tid < 192) {                           // basefold for dense1 (R7 strided)
        int c = tid >> 6, f = tid & 63;
        const float* wp = Wd32 + (size_t)(c * 64) * 64 + f;
        float a = 0.f;
        for (int d = 0; d < 64; ++d) a += carry[d] * wp[d * 64];
        basearr[tid] = bias[tid] + INVN * a;
    }
    __syncthreads();                           // B3: bounce + basearr

    // dense1 MFMA
    f32x4 acc[3][4];
#pragma unroll
    for (int c = 0; c < 3; ++c) {
        const half8* bb = (const half8*)&bounce3[c][0];
        half8 a0 = bb[(w * 16 + lm) * 9 + lq];
        half8 a1 = bb[(w * 16 + lm) * 9 + 4 + lq];
#pragma unroll
        for (int nt = 0; nt < 4; ++nt) {
            const half8* bp = (const half8*)(W16 + (size_t)(c * 64 + nt * 16 + lm) * 64);
            f32x4 t = {0.f, 0.f, 0.f, 0.f};
            t = __builtin_amdgcn_mfma_f32_16x16x32_f16(a0, bp[lq],     t, 0, 0, 0);
            t = __builtin_amdgcn_mfma_f32_16x16x32_f16(a1, bp[4 + lq], t, 0, 0, 0);
            acc[c][nt] = t;
        }
    }

    // relu + scan + shuffle
    float s[3][4][4], wexcl[3][4];
#pragma unroll
    for (int c = 0; c < 3; ++c)
#pragma unroll
        for (int nt = 0; nt < 4; ++nt) {
            float base = basearr[c * 64 + nt * 16 + lm];
            float run = 0.f;
#pragma unroll
            for (int r = 0; r < 4; ++r) {
                float yv = fmaxf(base + INVN * acc[c][nt][r], 0.f);
                run += yv; s[c][nt][r] = run;
            }
            float v = run;
            float t1 = __shfl_up(v, 16); if (lq >= 1) v += t1;
            float t2 = __shfl_up(v, 32); if (lq >= 2) v += t2;
            wexcl[c][nt] = v - run;
            if (lq == 3) segwt[c][w][nt * 16 + lm] = v;   // wave totals
        }
    __syncthreads();                           // B4: wave tops

    {
        float off[3][4], tot[3][4];
#pragma unroll
        for (int c = 0; c < 3; ++c)
#pragma unroll
            for (int nt = 0; nt < 4; ++nt) {
                float o = wexcl[c][nt], ts = 0.f;
#pragma unroll
                for (int w2 = 0; w2 < 4; ++w2) {
                    float wv = segwt[c][w2][nt * 16 + lm];
                    ts += wv;
                    if (w2 < w) o += wv;
                }
                off[c][nt] = o; tot[c][nt] = ts;
            }
        if (w == 0 && lq == 0)
#pragma unroll
            for (int nt = 0; nt < 4; ++nt) {
                float t3 = tot[0][nt] + tot[1][nt] + tot[2][nt];
                A64[(size_t)(b * CI + ci) * 64 + nt * 16 + lm] = t3;
                atomicAdd(&Ggrp[(size_t)(b * NG + g) * 64 + nt * 16 + lm], t3);
            }
#pragma unroll
        for (int nt = 0; nt < 4; ++nt)
#pragma unroll
            for (int r = 0; r < 4; ++r) {
                float S0 = off[0][nt] + s[0][nt][r];
                float S1 = off[1][nt] + s[1][nt][r];
                float S2 = off[2][nt] + s[2][nt][r];
                float P1 = off[1][nt] + (r ? s[1][nt][r - 1] : 0.f);
                float P2 = off[2][nt] + (r ? s[2][nt][r - 1] : 0.f);
                int row = w * 16 + lq * 4 + r;
                bounce3[0][row * 72 + nt * 16 + lm] = (_Float16)(S0 + P1 + P2);
                bounce3[1][row * 72 + nt * 16 + lm] = (_Float16)(S0 + S1 + P2);
                bounce3[2][row * 72 + nt * 16 + lm] = (_Float16)(S0 + S1 + S2);
            }
    }
    __syncthreads();                           // B5: store staging
#pragma unroll
    for (int q = 0; q < 6; ++q) {
        int idx = q * 256 + tid;
        int c = idx >> 9, rem = idx & 511;
        int pix = rem >> 3, f8 = rem & 7;
        half8 v = *(const half8*)&bounce3[c][pix * 72 + f8 * 8];
        ((half8*)(Y + ((size_t)(b * 3 + c) * SP + P0 + pix) * 64))[f8] = v;
    }
}

// ---------------- midB: wave-per-chunk dense2, Y in-place -------------------
__global__ __launch_bounds__(256, 3)
void midB(const _Float16* __restrict__ Yin, _Float16* __restrict__ Yout,
          const float* __restrict__ A64p, const float* __restrict__ Ggrp_p,
          const _Float16* __restrict__ W16, const float* __restrict__ WT32,
          const float* __restrict__ bias,
          float* __restrict__ A64, float* __restrict__ Ggrp)
{
    __shared__ float cpart[4][64];
    __shared__ float carry4[4][64];
    __shared__ float basearr4[4][192];
    __shared__ __align__(16) _Float16 wb[4][16 * 72];   // per-wave staging

    int tid = threadIdx.x, bi = blockIdx.x;
    int b = bi >> 8, cb = bi & 255;
    int ci0 = cb * 4, g = cb >> 4, cr0 = ci0 & 63;
    int w = tid >> 6, ln = tid & 63, lm = ln & 15, lq = ln >> 4;
    int ci = ci0 + w;                          // this wave's chunk
    int P0 = ci * 64;

    {   // shared prefix split across waves
        float s = 0.f;
        for (int j = w; j < g; j += 4)
            s += Ggrp_p[(size_t)(b * NG + j) * 64 + ln];
        const float* ap = A64p + (size_t)(b * CI + g * 64) * 64 + ln;
        for (int j = w; j < cr0; j += 4) s += ap[j * 64];
        cpart[w][ln] = s;
    }
    __syncthreads();                           // P1
    {   // per-wave carry
        float cw = cpart[0][ln] + cpart[1][ln] + cpart[2][ln] + cpart[3][ln];
        const float* ap = A64p + (size_t)(b * CI + ci0) * 64 + ln;
        for (int t = 0; t < w; ++t) cw += ap[t * 64];
        carry4[w][ln] = cw;
    }
    __syncthreads();                           // P2
    if (tid < 192) {                           // 4 basearrs, one weight pass
        int c = tid >> 6, f = tid & 63;
        const float* wp = WT32 + (size_t)(c * 64 + f) * 64;
        float a0 = 0.f, a1 = 0.f, a2 = 0.f, a3 = 0.f;
#pragma unroll 8
        for (int d = 0; d < 64; ++d) {
            float wv = wp[d];
            a0 += carry4[0][d] * wv; a1 += carry4[1][d] * wv;
            a2 += carry4[2][d] * wv; a3 += carry4[3][d] * wv;
        }
        float bz = bias[tid];
        basearr4[0][tid] = bz + INVN * a0;
        basearr4[1][tid] = bz + INVN * a1;
        basearr4[2][tid] = bz + INVN * a2;
        basearr4[3][tid] = bz + INVN * a3;
    }
    __syncthreads();                           // P3 -- last block-wide barrier

    float bse[3][4];
#pragma unroll
    for (int c = 0; c < 3; ++c)
#pragma unroll
        for (int nt = 0; nt < 4; ++nt)
            bse[c][nt] = basearr4[w][c * 64 + nt * 16 + lm];
    float roff[3][4] = {{0.f,0.f,0.f,0.f},{0.f,0.f,0.f,0.f},{0.f,0.f,0.f,0.f}};
    _Float16* wbw = &wb[w][0];

    // prologue: quad 0 A-frags
    half8 a0c[3], a1c[3];
#pragma unroll
    for (int c = 0; c < 3; ++c) {
        const half8* ap = (const half8*)(Yin + ((size_t)(b * 3 + c) * SP + P0 + lm) * 64);
        a0c[c] = ap[lq]; a1c[c] = ap[4 + lq];
    }

#pragma unroll 1
    for (int pq = 0; pq < 4; ++pq) {
        // prefetch next quad (in flight across this quad's compute)
        half8 n0c[3], n1c[3];
        if (pq < 3) {
#pragma unroll
            for (int c = 0; c < 3; ++c) {
                const half8* ap = (const half8*)(Yin +
                    ((size_t)(b * 3 + c) * SP + P0 + (pq + 1) * 16 + lm) * 64);
                n0c[c] = ap[lq]; n1c[c] = ap[4 + lq];
            }
        }

        f32x4 acc[3][4];
#pragma unroll
        for (int c = 0; c < 3; ++c)
#pragma unroll
            for (int nt = 0; nt < 4; ++nt) {
                const half8* bp = (const half8*)(W16 + (size_t)(c * 64 + nt * 16 + lm) * 64);
                f32x4 t = {0.f, 0.f, 0.f, 0.f};
                t = __builtin_amdgcn_mfma_f32_16x16x32_f16(a0c[c], bp[lq],     t, 0, 0, 0);
                t = __builtin_amdgcn_mfma_f32_16x16x32_f16(a1c[c], bp[4 + lq], t, 0, 0, 0);
                acc[c][nt] = t;
            }

        float s[3][4][4], off[3][4];
#pragma unroll
        for (int c = 0; c < 3; ++c)
#pragma unroll
            for (int nt = 0; nt < 4; ++nt) {
                float base = bse[c][nt];
                float run = 0.f;
#pragma unroll
                for (int r = 0; r < 4; ++r) {
                    float yv = fmaxf(base + INVN * acc[c][nt][r], 0.f);
                    run += yv; s[c][nt][r] = run;
                }
                float v = run;
                float t1 = __shfl_up(v, 16); if (lq >= 1) v += t1;
                float t2 = __shfl_up(v, 32); if (lq >= 2) v += t2;
                off[c][nt] = roff[c][nt] + (v - run);
                roff[c][nt] += __shfl(v, 48 + lm);   // quad total broadcast
            }

        // stage + vectorized store per channel (wave-private wb, in-wave order)
#pragma unroll
        for (int c = 0; c < 3; ++c) {
#pragma unroll
            for (int nt = 0; nt < 4; ++nt) {
                float offT = off[0][nt] + off[1][nt] + off[2][nt];
#pragma unroll
                for (int r = 0; r < 4; ++r) {
                    float s1p = r ? s[1][nt][r - 1] : 0.f;
                    float s2p = r ? s[2][nt][r - 1] : 0.f;
                    float V = offT + s[0][nt][r];
                    float ov = (c == 0) ? (V + s1p + s2p)
                             : (c == 1) ? (V + s[1][nt][r] + s2p)
                                        : (V + s[1][nt][r] + s[2][nt][r]);
                    wbw[(lq * 4 + r) * 72 + nt * 16 + lm] = (_Float16)ov;
                }
            }
            const half8* bb = (const half8*)wbw;
            _Float16* Yc = Yout + ((size_t)(b * 3 + c) * SP + P0 + pq * 16) * 64;
#pragma unroll
            for (int q = 0; q < 2; ++q) {
                int idx = q * 64 + ln, pix = idx >> 3, f8 = idx & 7;
                ((half8*)(Yc + (size_t)pix * 64))[f8] = bb[pix * 9 + f8];
            }
        }

        if (pq < 3) {
#pragma unroll
            for (int c = 0; c < 3; ++c) { a0c[c] = n0c[c]; a1c[c] = n1c[c]; }
        }
    }

    if (lq == 0)
#pragma unroll
        for (int nt = 0; nt < 4; ++nt) {
            float t3 = roff[0][nt] + roff[1][nt] + roff[2][nt];
            A64[(size_t)(b * CI + ci) * 64 + nt * 16 + lm] = t3;
            atomicAdd(&Ggrp[(size_t)(b * NG + g) * 64 + nt * 16 + lm], t3);
        }
}

// ---------------- midC: wave-per-chunk dense3 + final dense -> out ----------
__global__ __launch_bounds__(256, 3)
void midC(const _Float16* __restrict__ Yin,
          const float* __restrict__ A64p, const float* __restrict__ Ggrp_p,
          const _Float16* __restrict__ W16, const float* __restrict__ WT32,
          const float* __restrict__ bias,
          const _Float16* __restrict__ Wf16p, const float* __restrict__ bfin,
          float* __restrict__ out, float* __restrict__ A64, float* __restrict__ Ggrp)
{
    __shared__ float cpart[4][64];
    __shared__ float carry4[4][64];
    __shared__ float basearr4[4][192];
    __shared__ __align__(16) _Float16 wb[4][16 * 72];
    __shared__ __align__(16) float outst[4][16 * 28];   // per-wave out staging

    int tid = threadIdx.x, bi = blockIdx.x;
    int b = bi >> 8, cb = bi & 255;
    int ci0 = cb * 4, g = cb >> 4, cr0 = ci0 & 63;
    int w = tid >> 6, ln = tid & 63, lm = ln & 15, lq = ln >> 4;
    int ci = ci0 + w;
    int P0 = ci * 64;

    {
        float s = 0.f;
        for (int j = w; j < g; j += 4)
            s += Ggrp_p[(size_t)(b * NG + j) * 64 + ln];
        const float* ap = A64p + (size_t)(b * CI + g * 64) * 64 + ln;
        for (int j = w; j < cr0; j += 4) s += ap[j * 64];
        cpart[w][ln] = s;
    }
    __syncthreads();                           // P1
    {
        float cw = cpart[0][ln] + cpart[1][ln] + cpart[2][ln] + cpart[3][ln];
        const float* ap = A64p + (size_t)(b * CI + ci0) * 64 + ln;
        for (int t = 0; t < w; ++t) cw += ap[t * 64];
        carry4[w][ln] = cw;
    }
    __syncthreads();                           // P2
    if (tid < 192) {
        int c = tid >> 6, f = tid & 63;
        const float* wp = WT32 + (size_t)(c * 64 + f) * 64;
        float a0 = 0.f, a1 = 0.f, a2 = 0.f, a3 = 0.f;
#pragma unroll 8
        for (int d = 0; d < 64; ++d) {
            float wv = wp[d];
            a0 += carry4[0][d] * wv; a1 += carry4[1][d] * wv;
            a2 += carry4[2][d] * wv; a3 += carry4[3][d] * wv;
        }
        float bz = bias[tid];
        basearr4[0][tid] = bz + INVN * a0;
        basearr4[1][tid] = bz + INVN * a1;
        basearr4[2][tid] = bz + INVN * a2;
        basearr4[3][tid] = bz + INVN * a3;
    }
    __syncthreads();                           // P3 -- last block-wide barrier

    float bse[3][4];
#pragma unroll
    for (int c = 0; c < 3; ++c)
#pragma unroll
        for (int nt = 0; nt < 4; ++nt)
            bse[c][nt] = basearr4[w][c * 64 + nt * 16 + lm];
    float roff[3][4] = {{0.f,0.f,0.f,0.f},{0.f,0.f,0.f,0.f},{0.f,0.f,0.f,0.f}};
    _Float16* wbw = &wb[w][0];
    float* outw = &outst[w][0];

    half8 a0c[3], a1c[3];
#pragma unroll
    for (int c = 0; c < 3; ++c) {
        const half8* ap = (const half8*)(Yin + ((size_t)(b * 3 + c) * SP + P0 + lm) * 64);
        a0c[c] = ap[lq]; a1c[c] = ap[4 + lq];
    }

#pragma unroll 1
    for (int pq = 0; pq < 4; ++pq) {
        half8 n0c[3], n1c[3];
        if (pq < 3) {
#pragma unroll
            for (int c = 0; c < 3; ++c) {
                const half8* ap = (const half8*)(Yin +
                    ((size_t)(b * 3 + c) * SP + P0 + (pq + 1) * 16 + lm) * 64);
                n0c[c] = ap[lq]; n1c[c] = ap[4 + lq];
            }
        }

        f32x4 acc[3][4];
#pragma unroll
        for (int c = 0; c < 3; ++c)
#pragma unroll
            for (int nt = 0; nt < 4; ++nt) {
                const half8* bp = (const half8*)(W16 + (size_t)(c * 64 + nt * 16 + lm) * 64);
                f32x4 t = {0.f, 0.f, 0.f, 0.f};
                t = __builtin_amdgcn_mfma_f32_16x16x32_f16(a0c[c], bp[lq],     t, 0, 0, 0);
                t = __builtin_amdgcn_mfma_f32_16x16x32_f16(a1c[c], bp[4 + lq], t, 0, 0, 0);
                acc[c][nt] = t;
            }

        float s[3][4][4], off[3][4];
#pragma unroll
        for (int c = 0; c < 3; ++c)
#pragma unroll
            for (int nt = 0; nt < 4; ++nt) {
                float base = bse[c][nt];
                float run = 0.f;
#pragma unroll
                for (int r = 0; r < 4; ++r) {
                    float yv = fmaxf(base + INVN * acc[c][nt][r], 0.f);
                    run += yv; s[c][nt][r] = run;
                }
                float v = run;
                float t1 = __shfl_up(v, 16); if (lq >= 1) v += t1;
                float t2 = __shfl_up(v, 32); if (lq >= 2) v += t2;
                off[c][nt] = roff[c][nt] + (v - run);
                roff[c][nt] += __shfl(v, 48 + lm);
            }

        // per-channel: stage layer-3 values in wb, final dense MFMA -> outst
#pragma unroll
        for (int c = 0; c < 3; ++c) {
#pragma unroll
            for (int nt = 0; nt < 4; ++nt) {
                float offT = off[0][nt] + off[1][nt] + off[2][nt];
#pragma unroll
                for (int r = 0; r < 4; ++r) {
                    float s1p = r ? s[1][nt][r - 1] : 0.f;
                    float s2p = r ? s[2][nt][r - 1] : 0.f;
                    float V = offT + s[0][nt][r];
                    float ov = (c == 0) ? (V + s1p + s2p)
                             : (c == 1) ? (V + s[1][nt][r] + s2p)
                                        : (V + s[1][nt][r] + s[2][nt][r]);
                    wbw[(lq * 4 + r) * 72 + nt * 16 + lm] = (_Float16)ov;
                }
            }
            const half8* bb = (const half8*)wbw;
            half8 fa0 = bb[lm * 9 + lq];
            half8 fa1 = bb[lm * 9 + 4 + lq];
            const half8* fb = (const half8*)(Wf16p + (size_t)(c * 16 + lm) * 64);
            f32x4 t = {0.f, 0.f, 0.f, 0.f};
            t = __builtin_amdgcn_mfma_f32_16x16x32_f16(fa0, fb[lq],     t, 0, 0, 0);
            t = __builtin_amdgcn_mfma_f32_16x16x32_f16(fa1, fb[4 + lq], t, 0, 0, 0);
            if (lm < 8) {
                float bz = bfin[c * 8 + lm];
#pragma unroll
                for (int r = 0; r < 4; ++r)
                    outw[(lq * 4 + r) * 28 + c * 8 + lm] = bz + INVN * t[r];
            }
        }
        // quad's out written ONCE as full float4 lines (16px x 24f = 96 f4)
        {
            float4* obq = (float4*)(out + ((size_t)b * SS +
                                           (size_t)(P0 + pq * 16) * 3) * 8);
#pragma unroll
            for (int k = 0; k < 2; ++k) {
                int idx = k * 64 + ln;
                if (idx < 96) {
                    int pix = idx / 6, sub = (idx % 6) * 4;
                    obq[idx] = *(const float4*)&outw[pix * 28 + sub];
                }
            }
        }

        if (pq < 3) {
#pragma unroll
            for (int c = 0; c < 3; ++c) { a0c[c] = n0c[c]; a1c[c] = n1c[c]; }
        }
    }

    if (lq == 0)
#pragma unroll
        for (int nt = 0; nt < 4; ++nt) {
            float t3 = roff[0][nt] + roff[1][nt] + roff[2][nt];
            A64[(size_t)(b * CI + ci) * 64 + nt * 16 + lm] = t3;
            atomicAdd(&Ggrp[(size_t)(b * NG + g) * 64 + nt * 16 + lm], t3);
        }
}

// ---------------- fixk: out += INVN * Wf . carry3 ---------------------------
__global__ __launch_bounds__(256, 4)
void fixk(const float* __restrict__ A64p, const float* __restrict__ Ggrp_p,
          const float* __restrict__ Wf32, float* __restrict__ out)
{
    __shared__ float cpart[4][64];
    __shared__ float carry[64];
    __shared__ float part[24][8];
    __shared__ float vfix[24];
    int tid = threadIdx.x, bi = blockIdx.x;
    int b = bi >> 10, ci = bi & 1023, g = ci >> 6, cr = ci & 63;
    int w = tid >> 6, ln = tid & 63;
    int P0 = ci * 64;

    {
        float s = 0.f;
        for (int j = w; j < g; j += 4)
            s += Ggrp_p[(size_t)(b * NG + j) * 64 + ln];
        const float* ap = A64p + (size_t)(b * CI + g * 64) * 64 + ln;
        for (int j = w; j < cr; j += 4) s += ap[j * 64];
        cpart[w][ln] = s;
    }
    __syncthreads();
    if (tid < 64)
        carry[tid] = cpart[0][tid] + cpart[1][tid] + cpart[2][tid] + cpart[3][tid];
    __syncthreads();
    if (tid < 192) {                           // 24 outputs x 8 segments
        int ck = tid >> 3, sg = tid & 7;
        const float* wp = Wf32 + ck * 64 + sg * 8;
        const float* cp = carry + sg * 8;
        float vf = 0.f;
#pragma unroll
        for (int d = 0; d < 8; ++d) vf += cp[d] * wp[d];
        part[ck][sg] = vf;
    }
    __syncthreads();
    if (tid < 24) {
        float vf = 0.f;
#pragma unroll
        for (int j = 0; j < 8; ++j) vf += part[tid][j];
        vfix[tid] = INVN * vf;
    }
    __syncthreads();
    float4* obase = (float4*)(out + ((size_t)b * SS + (size_t)P0 * 3) * 8);
#pragma unroll
    for (int k = 0; k < 2; ++k) {
        int idx = k * 256 + tid;
        if (idx < 384) {
            int sub = (idx % 6) * 4;
            float4 v = obase[idx];
            v.x += vfix[sub];
            v.y += vfix[sub + 1];
            v.z += vfix[sub + 2];
            v.w += vfix[sub + 3];
            obase[idx] = v;
        }
    }
}

// ---------------- host -------------------------------------------------------
extern "C" void kernel_launch(void* const* d_in, const int* in_sizes, int n_in,
                              void* d_out, int out_size, void* d_ws, size_t ws_size,
                              hipStream_t stream)
{
    const int*   ex   = (const int*)d_in[0];
    const float* W0   = (const float*)d_in[1];
    const float* b0   = (const float*)d_in[2];
    const float* Wr   = (const float*)d_in[3];
    const float* br   = (const float*)d_in[4];
    const float* Wfin = (const float*)d_in[5];
    const float* bfin = (const float*)d_in[6];
    float* out = (float*)d_out;

    char* ws = (char*)d_ws;
    size_t off = 0;
    _Float16* Y = (_Float16*)(ws + off); off += (size_t)BB * 3 * SP * 64 * 2;  // 100.7 MB
    float* Ggrp1 = (float*)(ws + off); off += (size_t)BB * NG * 64 * 4;        // contiguous
    float* Ggrp2 = (float*)(ws + off); off += (size_t)BB * NG * 64 * 4;
    float* Ggrp3 = (float*)(ws + off); off += (size_t)BB * NG * 64 * 4;
    float* A64_1 = (float*)(ws + off); off += (size_t)BB * CI * 64 * 4;
    float* A64_2 = (float*)(ws + off); off += (size_t)BB * CI * 64 * 4;
    float* A64_3 = (float*)(ws + off); off += (size_t)BB * CI * 64 * 4;
    int* Hsub = (int*)(ws + off); off += (size_t)BB * CI * 24 * 4;
    int* Hqrt = (int*)(ws + off); off += (size_t)BB * NG * 4 * 24 * 4;
    _Float16* Wt16  = (_Float16*)(ws + off); off += 36864 * 2;
    float* Wd32T = (float*)(ws + off); off += 36864 * 4;
    _Float16* Wf16p = (_Float16*)(ws + off); off += 3072 * 2;
    float* Wf32  = (float*)(ws + off); off += 1536 * 4;
    float* tab32 = (float*)(ws + off); off += 1536 * 4;

    prep<<<256, 256, 0, stream>>>(ex, W0, b0, Wr, Wfin,
                                  Wt16, Wd32T, Wf16p, Wf32, tab32,
                                  Hsub, Hqrt, Ggrp1);
    midA<<<4096, 256, 0, stream>>>(ex, Hsub, Hqrt, tab32,
                                   Wt16, Wr, br, Y, A64_1, Ggrp1);
    midB<<<1024, 256, 0, stream>>>(Y, Y, A64_1, Ggrp1,
                                   Wt16 + 12288, Wd32T + 12288, br + 192,
                                   A64_2, Ggrp2);
    midC<<<1024, 256, 0, stream>>>(Y, A64_2, Ggrp2,
                                   Wt16 + 24576, Wd32T + 24576, br + 384,
                                   Wf16p, bfin, out, A64_3, Ggrp3);
    fixk<<<4096, 256, 0, stream>>>(A64_3, Ggrp3, Wf32, out);
}

// Round 7
// 358.586 us; speedup vs baseline: 1.3654x; 1.3654x over previous
//
#include <hip/hip_runtime.h>
#include <stdint.h>

// ---------------------------------------------------------------------------
// R14: compound ONLY proven wins onto the R7 baseline (365 us; best-ever).
// Scorecard: every structural rewrite R8-R13 lost to R7 (spills at unified
// VGPR+AGPR cap, or barrier-phase overhead, or store RMW amplification).
// R7's (256,4) block-convoy mid bodies are the only spill-free clean-traffic
// form measured. This round:
//  - mid bodies BYTE-IDENTICAL to R7 (midA's only delta: reads non-atomic
//    Hqrt quarter-sums, validated in R12 with identical absmax).
//  - prep: 256 blocks (R12-proven), absorbs Ggrp zeroing + Hqrt (no memsets,
//    8 dispatches -> 6).
//  - fixk: 24x64 dot distributed over 192 threads (R10+-proven).
// Next isolated experiment (if this lands ~335): standalone carry kernel to
// pre-stage basearr and strip midB's B1-B3 prologue.
// ---------------------------------------------------------------------------

#define BB 4
#define SP 65536
#define SS 196608
#define CI 1024                 // 64-px chunks per batch
#define NG 16                   // groups per batch (64 chunks each)
#define INVN (1.0f / 196608.0f)

typedef __attribute__((ext_vector_type(8))) _Float16 half8;
typedef __attribute__((ext_vector_type(4))) float    f32x4;

// ---------------- prep: histograms + weight prep + Ggrp zero ----------------
__global__ __launch_bounds__(256)
void prep(const int* __restrict__ ex, const float* __restrict__ W0,
          const float* __restrict__ b0, const float* __restrict__ Wr,
          const float* __restrict__ Wfin,
          _Float16* __restrict__ Wt16, _Float16* __restrict__ Wf16p,
          float* __restrict__ Wf32, float* __restrict__ tab32,
          int* __restrict__ Hsub, int* __restrict__ Hqrt,
          float* __restrict__ Gz)
{
    __shared__ int hist[16][24];
    int tid = threadIdx.x, bi = blockIdx.x;        // 256 blocks
    int b = bi >> 6, g = (bi >> 2) & 15, q = bi & 3;  // quarter-group = 16 chunks
    for (int i = tid; i < 384; i += 256) hist[i / 24][i % 24] = 0;
    __syncthreads();
    for (int it = 0; it < 4; ++it) {
        int pl = it * 256 + tid;                   // 0..1023 within quarter
        const int* ep = ex + ((size_t)b * SP + g * 4096 + q * 1024 + pl) * 3;
        int j = pl >> 6;                           // chunk within quarter
        atomicAdd(&hist[j][ep[0]], 1);
        atomicAdd(&hist[j][8 + ep[1]], 1);
        atomicAdd(&hist[j][16 + ep[2]], 1);
    }
    __syncthreads();
    for (int i = tid; i < 384; i += 256) {
        int j = i / 24, cv = i % 24;
        Hsub[(size_t)(b * CI + g * 64 + q * 16 + j) * 24 + cv] = hist[j][cv];
    }
    if (tid < 24) {
        int s = 0;
        for (int j = 0; j < 16; ++j) s += hist[j][tid];
        Hqrt[((size_t)(b * NG + g) * 4 + q) * 24 + tid] = s;   // non-atomic
    }
    {   // weight prep + Ggrp zeroing (all 256 blocks share)
        int i0 = bi * 256 + tid, nth = 256 * 256;
        for (int idx = i0; idx < 12288; idx += nth)     // Ggrp1..3 zero
            Gz[idx] = 0.f;
        for (int idx = i0; idx < 36864; idx += nth) {   // Wt16[l][c][f][d]
            int d = idx & 63, f = (idx >> 6) & 63, lc = idx >> 12;
            Wt16[idx] = (_Float16)Wr[(size_t)(lc * 64 + d) * 64 + f];
        }
        for (int idx = i0; idx < 3072; idx += nth) {    // Wf16p[c][n16][d]
            int d = idx & 63, n = (idx >> 6) & 15, c = idx >> 10;
            Wf16p[idx] = (n < 8) ? (_Float16)Wfin[(size_t)(c * 64 + d) * 8 + n]
                                 : (_Float16)0.f;
        }
        for (int idx = i0; idx < 1536; idx += nth) {    // Wf32[ck][d]
            int d = idx & 63, ck = idx >> 6;
            Wf32[idx] = Wfin[(size_t)((ck >> 3) * 64 + d) * 8 + (ck & 7)];
        }
        for (int idx = i0; idx < 1536; idx += nth) {    // tab32[cv][f]
            int f = idx & 63, v = (idx >> 6) & 7, c = idx >> 9;
            float xv = v * 0.25f - 1.0f;
            tab32[idx] = fmaxf(W0[c * 64 + f] * xv + b0[c * 64 + f], 0.f);
        }
    }
}

// ---------------- midA: R7-exact layer0 (LUT, hist carry) + dense1 -> Y -----
__global__ __launch_bounds__(256, 4)
void midA(const int* __restrict__ ex,
          const int* __restrict__ Hsub, const int* __restrict__ Hqrt,
          const float* __restrict__ tab32,
          const _Float16* __restrict__ W16, const float* __restrict__ Wd32,
          const float* __restrict__ bias, _Float16* __restrict__ Y,
          float* __restrict__ A64, float* __restrict__ Ggrp)
{
    __shared__ float stab[1536];
    __shared__ __align__(16) _Float16 bounce3[3][64 * 72];
    __shared__ float segwt[3][4][64];
    __shared__ float basearr[192];
    __shared__ float hpart[4][24];
    __shared__ float carry[64];

    int tid = threadIdx.x, bi = blockIdx.x;
    int b = bi >> 10, ci = bi & 1023, g = ci >> 6, cr = ci & 63;
    int w = tid >> 6, ln = tid & 63, lm = ln & 15, lq = ln >> 4;
    int P0 = ci * 64;

    for (int i = tid; i < 1536; i += 256) stab[i] = tab32[i];
    if (ln < 24) {                             // distributed hist prefix
        float s = 0.f;
        for (int j = w; j < g; j += 4) {
            const int* hq = Hqrt + ((size_t)(b * NG + j) * 4) * 24 + ln;
            s += (float)(hq[0] + hq[24] + hq[48] + hq[72]);
        }
        const int* hp = Hsub + (size_t)(b * CI + g * 64) * 24 + ln;
        for (int j = w; j < cr; j += 4) s += (float)hp[j * 24];
        hpart[w][ln] = s;
    }
    __syncthreads();                           // B1: stab + hpart

    // layer-0 local values: thread (f=ln, seg=w) scans 16 px
    float y0[3][16];
    {
#pragma unroll
        for (int p = 0; p < 16; ++p) {
            const int* ep = ex + ((size_t)b * SP + P0 + w * 16 + p) * 3;
            y0[0][p] = stab[ep[0] * 64 + ln];
            y0[1][p] = stab[(8 + ep[1]) * 64 + ln];
            y0[2][p] = stab[(16 + ep[2]) * 64 + ln];
        }
#pragma unroll
        for (int c = 0; c < 3; ++c)
#pragma unroll
            for (int p = 1; p < 16; ++p) y0[c][p] += y0[c][p - 1];
#pragma unroll
        for (int c = 0; c < 3; ++c) segwt[c][w][ln] = y0[c][15];
    }
    if (tid < 64) {                            // layer-0 carry from hist
        float c0 = 0.f;
#pragma unroll
        for (int cv = 0; cv < 24; ++cv) {
            float cnt = hpart[0][cv] + hpart[1][cv] + hpart[2][cv] + hpart[3][cv];
            c0 += cnt * stab[cv * 64 + tid];
        }
        carry[tid] = c0;
    }
    __syncthreads();                           // B2: segwt + carry

    {   // combine channels -> bounce (layer-0 chunk-local flattened cumsum)
        float off0[3];
#pragma unroll
        for (int c = 0; c < 3; ++c) {
            float o = 0.f;
            for (int w2 = 0; w2 < w; ++w2) o += segwt[c][w2][ln];
            off0[c] = o;
        }
#pragma unroll
        for (int p = 0; p < 16; ++p) {
            float S0 = y0[0][p] + off0[0], S1 = y0[1][p] + off0[1], S2 = y0[2][p] + off0[2];
            float P1 = p ? y0[1][p - 1] + off0[1] : off0[1];
            float P2 = p ? y0[2][p - 1] + off0[2] : off0[2];
            int row = w * 16 + p;
            bounce3[0][row * 72 + ln] = (_Float16)(S0 + P1 + P2);
            bounce3[1][row * 72 + ln] = (_Float16)(S0 + S1 + P2);
            bounce3[2][row * 72 + ln] = (_Float16)(S0 + S1 + S2);
        }
    }
    if (tid < 192) {                           // basefold for dense1
        int c = tid >> 6, f = tid & 63;
        const float* wp = Wd32 + (size_t)(c * 64) * 64 + f;
        float a = 0.f;
        for (int d = 0; d < 64; ++d) a += carry[d] * wp[d * 64];
        basearr[tid] = bias[tid] + INVN * a;
    }
    __syncthreads();                           // B3: bounce + basearr

    // dense1 MFMA
    f32x4 acc[3][4];
#pragma unroll
    for (int c = 0; c < 3; ++c) {
        const half8* bb = (const half8*)&bounce3[c][0];
        half8 a0 = bb[(w * 16 + lm) * 9 + lq];
        half8 a1 = bb[(w * 16 + lm) * 9 + 4 + lq];
#pragma unroll
        for (int nt = 0; nt < 4; ++nt) {
            const half8* bp = (const half8*)(W16 + (size_t)(c * 64 + nt * 16 + lm) * 64);
            f32x4 t = {0.f, 0.f, 0.f, 0.f};
            t = __builtin_amdgcn_mfma_f32_16x16x32_f16(a0, bp[lq],     t, 0, 0, 0);
            t = __builtin_amdgcn_mfma_f32_16x16x32_f16(a1, bp[4 + lq], t, 0, 0, 0);
            acc[c][nt] = t;
        }
    }

    // relu + scan + shuffle
    float s[3][4][4], wexcl[3][4];
#pragma unroll
    for (int c = 0; c < 3; ++c)
#pragma unroll
        for (int nt = 0; nt < 4; ++nt) {
            float base = basearr[c * 64 + nt * 16 + lm];
            float run = 0.f;
#pragma unroll
            for (int r = 0; r < 4; ++r) {
                float yv = fmaxf(base + INVN * acc[c][nt][r], 0.f);
                run += yv; s[c][nt][r] = run;
            }
            float v = run;
            float t1 = __shfl_up(v, 16); if (lq >= 1) v += t1;
            float t2 = __shfl_up(v, 32); if (lq >= 2) v += t2;
            wexcl[c][nt] = v - run;
            if (lq == 3) segwt[c][w][nt * 16 + lm] = v;   // wave totals
        }
    __syncthreads();                           // B4: wave tops

    {
        float off[3][4], tot[3][4];
#pragma unroll
        for (int c = 0; c < 3; ++c)
#pragma unroll
            for (int nt = 0; nt < 4; ++nt) {
                float o = wexcl[c][nt], ts = 0.f;
#pragma unroll
                for (int w2 = 0; w2 < 4; ++w2) {
                    float wv = segwt[c][w2][nt * 16 + lm];
                    ts += wv;
                    if (w2 < w) o += wv;
                }
                off[c][nt] = o; tot[c][nt] = ts;
            }
        if (w == 0 && lq == 0)
#pragma unroll
            for (int nt = 0; nt < 4; ++nt) {
                float t3 = tot[0][nt] + tot[1][nt] + tot[2][nt];
                A64[(size_t)(b * CI + ci) * 64 + nt * 16 + lm] = t3;
                atomicAdd(&Ggrp[(size_t)(b * NG + g) * 64 + nt * 16 + lm], t3);
            }
#pragma unroll
        for (int nt = 0; nt < 4; ++nt)
#pragma unroll
            for (int r = 0; r < 4; ++r) {
                float S0 = off[0][nt] + s[0][nt][r];
                float S1 = off[1][nt] + s[1][nt][r];
                float S2 = off[2][nt] + s[2][nt][r];
                float P1 = off[1][nt] + (r ? s[1][nt][r - 1] : 0.f);
                float P2 = off[2][nt] + (r ? s[2][nt][r - 1] : 0.f);
                int row = w * 16 + lq * 4 + r;
                bounce3[0][row * 72 + nt * 16 + lm] = (_Float16)(S0 + P1 + P2);
                bounce3[1][row * 72 + nt * 16 + lm] = (_Float16)(S0 + S1 + P2);
                bounce3[2][row * 72 + nt * 16 + lm] = (_Float16)(S0 + S1 + S2);
            }
    }
    __syncthreads();                           // B5: store staging
#pragma unroll
    for (int q = 0; q < 6; ++q) {
        int idx = q * 256 + tid;
        int c = idx >> 9, rem = idx & 511;
        int pix = rem >> 3, f8 = rem & 7;
        half8 v = *(const half8*)&bounce3[c][pix * 72 + f8 * 8];
        ((half8*)(Y + ((size_t)(b * 3 + c) * SP + P0 + pix) * 64))[f8] = v;
    }
}

// ---------------- midB: dense2, Y in-place (R7-exact) -----------------------
__global__ __launch_bounds__(256, 4)
void midB(const _Float16* Yin, _Float16* Yout,
          const float* __restrict__ A64p, const float* __restrict__ Ggrp_p,
          const _Float16* __restrict__ W16, const float* __restrict__ Wd32,
          const float* __restrict__ bias,
          float* __restrict__ A64, float* __restrict__ Ggrp)
{
    __shared__ __align__(16) _Float16 bounce3[3][64 * 72];
    __shared__ float wtop[3][4][64];
    __shared__ float basearr[192];
    __shared__ float cpart[4][64];
    __shared__ float carry[64];

    int tid = threadIdx.x, bi = blockIdx.x;
    int b = bi >> 10, ci = bi & 1023, g = ci >> 6, cr = ci & 63;
    int w = tid >> 6, ln = tid & 63, lm = ln & 15, lq = ln >> 4;
    int P0 = ci * 64;

    // A-frags first (latency hidden behind prologue)
    half8 af0[3], af1[3];
#pragma unroll
    for (int c = 0; c < 3; ++c) {
        const half8* ap = (const half8*)(Yin + ((size_t)(b * 3 + c) * SP + P0 + w * 16 + lm) * 64);
        af0[c] = ap[lq]; af1[c] = ap[4 + lq];
    }
    {   // distributed carry prefix
        float s = 0.f;
        for (int j = w; j < g; j += 4)
            s += Ggrp_p[(size_t)(b * NG + j) * 64 + ln];
        const float* ap = A64p + (size_t)(b * CI + g * 64) * 64 + ln;
        for (int j = w; j < cr; j += 4) s += ap[j * 64];
        cpart[w][ln] = s;
    }
    __syncthreads();                           // B1
    if (tid < 64)
        carry[tid] = cpart[0][tid] + cpart[1][tid] + cpart[2][tid] + cpart[3][tid];
    __syncthreads();                           // B2
    if (tid < 192) {
        int c = tid >> 6, f = tid & 63;
        const float* wp = Wd32 + (size_t)(c * 64) * 64 + f;
        float a = 0.f;
        for (int d = 0; d < 64; ++d) a += carry[d] * wp[d * 64];
        basearr[tid] = bias[tid] + INVN * a;
    }
    __syncthreads();                           // B3

    f32x4 acc[3][4];
#pragma unroll
    for (int c = 0; c < 3; ++c)
#pragma unroll
        for (int nt = 0; nt < 4; ++nt) {
            const half8* bp = (const half8*)(W16 + (size_t)(c * 64 + nt * 16 + lm) * 64);
            f32x4 t = {0.f, 0.f, 0.f, 0.f};
            t = __builtin_amdgcn_mfma_f32_16x16x32_f16(af0[c], bp[lq],     t, 0, 0, 0);
            t = __builtin_amdgcn_mfma_f32_16x16x32_f16(af1[c], bp[4 + lq], t, 0, 0, 0);
            acc[c][nt] = t;
        }

    float s[3][4][4], wexcl[3][4];
#pragma unroll
    for (int c = 0; c < 3; ++c)
#pragma unroll
        for (int nt = 0; nt < 4; ++nt) {
            float base = basearr[c * 64 + nt * 16 + lm];
            float run = 0.f;
#pragma unroll
            for (int r = 0; r < 4; ++r) {
                float yv = fmaxf(base + INVN * acc[c][nt][r], 0.f);
                run += yv; s[c][nt][r] = run;
            }
            float v = run;
            float t1 = __shfl_up(v, 16); if (lq >= 1) v += t1;
            float t2 = __shfl_up(v, 32); if (lq >= 2) v += t2;
            wexcl[c][nt] = v - run;
            if (lq == 3) wtop[c][w][nt * 16 + lm] = v;
        }
    __syncthreads();                           // B4

    {
        float off[3][4], tot[3][4];
#pragma unroll
        for (int c = 0; c < 3; ++c)
#pragma unroll
            for (int nt = 0; nt < 4; ++nt) {
                float o = wexcl[c][nt], ts = 0.f;
#pragma unroll
                for (int w2 = 0; w2 < 4; ++w2) {
                    float wv = wtop[c][w2][nt * 16 + lm];
                    ts += wv;
                    if (w2 < w) o += wv;
                }
                off[c][nt] = o; tot[c][nt] = ts;
            }
        if (w == 0 && lq == 0)
#pragma unroll
            for (int nt = 0; nt < 4; ++nt) {
                float t3 = tot[0][nt] + tot[1][nt] + tot[2][nt];
                A64[(size_t)(b * CI + ci) * 64 + nt * 16 + lm] = t3;
                atomicAdd(&Ggrp[(size_t)(b * NG + g) * 64 + nt * 16 + lm], t3);
            }
#pragma unroll
        for (int nt = 0; nt < 4; ++nt)
#pragma unroll
            for (int r = 0; r < 4; ++r) {
                float S0 = off[0][nt] + s[0][nt][r];
                float S1 = off[1][nt] + s[1][nt][r];
                float S2 = off[2][nt] + s[2][nt][r];
                float P1 = off[1][nt] + (r ? s[1][nt][r - 1] : 0.f);
                float P2 = off[2][nt] + (r ? s[2][nt][r - 1] : 0.f);
                int row = w * 16 + lq * 4 + r;
                bounce3[0][row * 72 + nt * 16 + lm] = (_Float16)(S0 + P1 + P2);
                bounce3[1][row * 72 + nt * 16 + lm] = (_Float16)(S0 + S1 + P2);
                bounce3[2][row * 72 + nt * 16 + lm] = (_Float16)(S0 + S1 + S2);
            }
    }
    __syncthreads();                           // B5
#pragma unroll
    for (int q = 0; q < 6; ++q) {
        int idx = q * 256 + tid;
        int c = idx >> 9, rem = idx & 511;
        int pix = rem >> 3, f8 = rem & 7;
        half8 v = *(const half8*)&bounce3[c][pix * 72 + f8 * 8];
        ((half8*)(Yout + ((size_t)(b * 3 + c) * SP + P0 + pix) * 64))[f8] = v;
    }
}

// ---------------- midC: dense3 + final MFMA -> out (R7-exact) ---------------
__global__ __launch_bounds__(256, 4)
void midC(const _Float16* __restrict__ Yin,
          const float* __restrict__ A64p, const float* __restrict__ Ggrp_p,
          const _Float16* __restrict__ W16, const float* __restrict__ Wd32,
          const float* __restrict__ bias,
          const _Float16* __restrict__ Wf16p, const float* __restrict__ bfin,
          float* __restrict__ out, float* __restrict__ A64, float* __restrict__ Ggrp)
{
    __shared__ __align__(16) _Float16 bounce3[3][64 * 72];
    __shared__ float wtop[3][4][64];
    __shared__ float basearr[192];
    __shared__ float cpart[4][64];
    __shared__ float carry[64];
    __shared__ __align__(16) float outst[64 * 28];

    int tid = threadIdx.x, bi = blockIdx.x;
    int b = bi >> 10, ci = bi & 1023, g = ci >> 6, cr = ci & 63;
    int w = tid >> 6, ln = tid & 63, lm = ln & 15, lq = ln >> 4;
    int P0 = ci * 64;

    half8 af0[3], af1[3];
#pragma unroll
    for (int c = 0; c < 3; ++c) {
        const half8* ap = (const half8*)(Yin + ((size_t)(b * 3 + c) * SP + P0 + w * 16 + lm) * 64);
        af0[c] = ap[lq]; af1[c] = ap[4 + lq];
    }
    {
        float s = 0.f;
        for (int j = w; j < g; j += 4)
            s += Ggrp_p[(size_t)(b * NG + j) * 64 + ln];
        const float* ap = A64p + (size_t)(b * CI + g * 64) * 64 + ln;
        for (int j = w; j < cr; j += 4) s += ap[j * 64];
        cpart[w][ln] = s;
    }
    __syncthreads();                           // B1
    if (tid < 64)
        carry[tid] = cpart[0][tid] + cpart[1][tid] + cpart[2][tid] + cpart[3][tid];
    __syncthreads();                           // B2
    if (tid < 192) {
        int c = tid >> 6, f = tid & 63;
        const float* wp = Wd32 + (size_t)(c * 64) * 64 + f;
        float a = 0.f;
        for (int d = 0; d < 64; ++d) a += carry[d] * wp[d * 64];
        basearr[tid] = bias[tid] + INVN * a;
    }
    __syncthreads();                           // B3

    f32x4 acc[3][4];
#pragma unroll
    for (int c = 0; c < 3; ++c)
#pragma unroll
        for (int nt = 0; nt < 4; ++nt) {
            const half8* bp = (const half8*)(W16 + (size_t)(c * 64 + nt * 16 + lm) * 64);
            f32x4 t = {0.f, 0.f, 0.f, 0.f};
            t = __builtin_amdgcn_mfma_f32_16x16x32_f16(af0[c], bp[lq],     t, 0, 0, 0);
            t = __builtin_amdgcn_mfma_f32_16x16x32_f16(af1[c], bp[4 + lq], t, 0, 0, 0);
            acc[c][nt] = t;
        }

    float s[3][4][4], wexcl[3][4];
#pragma unroll
    for (int c = 0; c < 3; ++c)
#pragma unroll
        for (int nt = 0; nt < 4; ++nt) {
            float base = basearr[c * 64 + nt * 16 + lm];
            float run = 0.f;
#pragma unroll
            for (int r = 0; r < 4; ++r) {
                float yv = fmaxf(base + INVN * acc[c][nt][r], 0.f);
                run += yv; s[c][nt][r] = run;
            }
            float v = run;
            float t1 = __shfl_up(v, 16); if (lq >= 1) v += t1;
            float t2 = __shfl_up(v, 32); if (lq >= 2) v += t2;
            wexcl[c][nt] = v - run;
            if (lq == 3) wtop[c][w][nt * 16 + lm] = v;
        }
    __syncthreads();                           // B4

    {
        float off[3][4], tot[3][4];
#pragma unroll
        for (int c = 0; c < 3; ++c)
#pragma unroll
            for (int nt = 0; nt < 4; ++nt) {
                float o = wexcl[c][nt], ts = 0.f;
#pragma unroll
                for (int w2 = 0; w2 < 4; ++w2) {
                    float wv = wtop[c][w2][nt * 16 + lm];
                    ts += wv;
                    if (w2 < w) o += wv;
                }
                off[c][nt] = o; tot[c][nt] = ts;
            }
        if (w == 0 && lq == 0)
#pragma unroll
            for (int nt = 0; nt < 4; ++nt) {
                float t3 = tot[0][nt] + tot[1][nt] + tot[2][nt];
                A64[(size_t)(b * CI + ci) * 64 + nt * 16 + lm] = t3;
                atomicAdd(&Ggrp[(size_t)(b * NG + g) * 64 + nt * 16 + lm], t3);
            }
#pragma unroll
        for (int nt = 0; nt < 4; ++nt)
#pragma unroll
            for (int r = 0; r < 4; ++r) {
                float S0 = off[0][nt] + s[0][nt][r];
                float S1 = off[1][nt] + s[1][nt][r];
                float S2 = off[2][nt] + s[2][nt][r];
                float P1 = off[1][nt] + (r ? s[1][nt][r - 1] : 0.f);
                float P2 = off[2][nt] + (r ? s[2][nt][r - 1] : 0.f);
                int row = w * 16 + lq * 4 + r;
                bounce3[0][row * 72 + nt * 16 + lm] = (_Float16)(S0 + P1 + P2);
                bounce3[1][row * 72 + nt * 16 + lm] = (_Float16)(S0 + S1 + P2);
                bounce3[2][row * 72 + nt * 16 + lm] = (_Float16)(S0 + S1 + S2);
            }
    }
    __syncthreads();                           // B5: layer-3 local staged

    // final dense via padded-Wf MFMA (n=16: 8 logits + 8 zero)
#pragma unroll
    for (int c = 0; c < 3; ++c) {
        const half8* bb = (const half8*)&bounce3[c][0];
        half8 fa0 = bb[(w * 16 + lm) * 9 + lq];
        half8 fa1 = bb[(w * 16 + lm) * 9 + 4 + lq];
        const half8* fb = (const half8*)(Wf16p + (size_t)(c * 16 + lm) * 64);
        f32x4 t = {0.f, 0.f, 0.f, 0.f};
        t = __builtin_amdgcn_mfma_f32_16x16x32_f16(fa0, fb[lq],     t, 0, 0, 0);
        t = __builtin_amdgcn_mfma_f32_16x16x32_f16(fa1, fb[4 + lq], t, 0, 0, 0);
        if (lm < 8) {
            float bz = bfin[c * 8 + lm];
#pragma unroll
            for (int r = 0; r < 4; ++r)
                outst[(w * 16 + lq * 4 + r) * 28 + c * 8 + lm] = bz + INVN * t[r];
        }
    }
    __syncthreads();                           // B6
    {   // 64 px x 24 floats = 384 float4
        float4* obase = (float4*)(out + ((size_t)b * SS + (size_t)P0 * 3) * 8);
#pragma unroll
        for (int k = 0; k < 2; ++k) {
            int idx = k * 256 + tid;
            if (idx < 384) {
                int pix = idx / 6, sub = (idx % 6) * 4;
                obase[idx] = *(const float4*)&outst[pix * 28 + sub];
            }
        }
    }
}

// ---------------- fixk: out += INVN * Wf . carry3 (distributed dot) ---------
__global__ __launch_bounds__(256, 4)
void fixk(const float* __restrict__ A64p, const float* __restrict__ Ggrp_p,
          const float* __restrict__ Wf32, float* __restrict__ out)
{
    __shared__ float cpart[4][64];
    __shared__ float carry[64];
    __shared__ float part[24][8];
    __shared__ float vfix[24];
    int tid = threadIdx.x, bi = blockIdx.x;
    int b = bi >> 10, ci = bi & 1023, g = ci >> 6, cr = ci & 63;
    int w = tid >> 6, ln = tid & 63;
    int P0 = ci * 64;

    {
        float s = 0.f;
        for (int j = w; j < g; j += 4)
            s += Ggrp_p[(size_t)(b * NG + j) * 64 + ln];
        const float* ap = A64p + (size_t)(b * CI + g * 64) * 64 + ln;
        for (int j = w; j < cr; j += 4) s += ap[j * 64];
        cpart[w][ln] = s;
    }
    __syncthreads();
    if (tid < 64)
        carry[tid] = cpart[0][tid] + cpart[1][tid] + cpart[2][tid] + cpart[3][tid];
    __syncthreads();
    if (tid < 192) {                           // 24 outputs x 8 segments
        int ck = tid >> 3, sg = tid & 7;
        const float* wp = Wf32 + ck * 64 + sg * 8;
        const float* cp = carry + sg * 8;
        float vf = 0.f;
#pragma unroll
        for (int d = 0; d < 8; ++d) vf += cp[d] * wp[d];
        part[ck][sg] = vf;
    }
    __syncthreads();
    if (tid < 24) {
        float vf = 0.f;
#pragma unroll
        for (int j = 0; j < 8; ++j) vf += part[tid][j];
        vfix[tid] = INVN * vf;
    }
    __syncthreads();
    float4* obase = (float4*)(out + ((size_t)b * SS + (size_t)P0 * 3) * 8);
#pragma unroll
    for (int k = 0; k < 2; ++k) {
        int idx = k * 256 + tid;
        if (idx < 384) {
            int sub = (idx % 6) * 4;
            float4 v = obase[idx];
            v.x += vfix[sub];
            v.y += vfix[sub + 1];
            v.z += vfix[sub + 2];
            v.w += vfix[sub + 3];
            obase[idx] = v;
        }
    }
}

// ---------------- host -------------------------------------------------------
extern "C" void kernel_launch(void* const* d_in, const int* in_sizes, int n_in,
                              void* d_out, int out_size, void* d_ws, size_t ws_size,
                              hipStream_t stream)
{
    const int*   ex   = (const int*)d_in[0];
    const float* W0   = (const float*)d_in[1];
    const float* b0   = (const float*)d_in[2];
    const float* Wr   = (const float*)d_in[3];
    const float* br   = (const float*)d_in[4];
    const float* Wfin = (const float*)d_in[5];
    const float* bfin = (const float*)d_in[6];
    float* out = (float*)d_out;

    char* ws = (char*)d_ws;
    size_t off = 0;
    _Float16* Y = (_Float16*)(ws + off); off += (size_t)BB * 3 * SP * 64 * 2;  // 100.7 MB
    float* Ggrp1 = (float*)(ws + off); off += (size_t)BB * NG * 64 * 4;        // contiguous
    float* Ggrp2 = (float*)(ws + off); off += (size_t)BB * NG * 64 * 4;
    float* Ggrp3 = (float*)(ws + off); off += (size_t)BB * NG * 64 * 4;
    float* A64_1 = (float*)(ws + off); off += (size_t)BB * CI * 64 * 4;
    float* A64_2 = (float*)(ws + off); off += (size_t)BB * CI * 64 * 4;
    float* A64_3 = (float*)(ws + off); off += (size_t)BB * CI * 64 * 4;
    int* Hsub = (int*)(ws + off); off += (size_t)BB * CI * 24 * 4;
    int* Hqrt = (int*)(ws + off); off += (size_t)BB * NG * 4 * 24 * 4;
    _Float16* Wt16  = (_Float16*)(ws + off); off += 36864 * 2;
    _Float16* Wf16p = (_Float16*)(ws + off); off += 3072 * 2;
    float* Wf32  = (float*)(ws + off); off += 1536 * 4;
    float* tab32 = (float*)(ws + off); off += 1536 * 4;

    prep<<<256, 256, 0, stream>>>(ex, W0, b0, Wr, Wfin,
                                  Wt16, Wf16p, Wf32, tab32,
                                  Hsub, Hqrt, Ggrp1);
    midA<<<4096, 256, 0, stream>>>(ex, Hsub, Hqrt, tab32,
                                   Wt16, Wr, br, Y, A64_1, Ggrp1);
    midB<<<4096, 256, 0, stream>>>(Y, Y, A64_1, Ggrp1,
                                   Wt16 + 12288, Wr + 12288, br + 192,
                                   A64_2, Ggrp2);
    midC<<<4096, 256, 0, stream>>>(Y, A64_2, Ggrp2,
                                   Wt16 + 24576, Wr + 24576, br + 384,
                                   Wf16p, bfin, out, A64_3, Ggrp3);
    fixk<<<4096, 256, 0, stream>>>(A64_3, Ggrp3, Wf32, out);
}